// Round 7
// baseline (380.283 us; speedup 1.0000x reference)
//
#include <hip/hip_runtime.h>
#include <hip/hip_bf16.h>

#define NPTS 262144
#define ROWS 64
// Fragment line = 64 lanes x 8 bf16 = 512 elems (1 KB). Line (r2, kt) holds
// B-fragment of mfma_32x32x16: lane l = point (l&31) of pt-tile r2,
// k-channels kt*16 + (l>>5)*8 + j.
#define BUF1_OFF 16384              // buf elems: 2 r2 x 16 kt x 512
#define XBUF_OFF 32768              // xbuf: x_emb [r2][kt4] 8 lines / d_emb [r2][kt2] 4 lines
#define LDS_BYTES ((16384*2 + 4096)*2)   // 73728 B -> 2 blocks/CU

typedef __attribute__((ext_vector_type(8)))  short short8;
typedef __attribute__((ext_vector_type(4)))  float f32x4;
typedef __attribute__((ext_vector_type(16))) float f32x16;

__device__ __forceinline__ ushort bfu(float f) {
  union { float f; unsigned u; } x; x.f = f;
  unsigned r = x.u + 0x7fffu + ((x.u >> 16) & 1u);
  return (ushort)(r >> 16);
}
__device__ __forceinline__ unsigned pk2(float a, float b) {
  __hip_bfloat162 h = __float22bfloat162_rn(float2{a, b});
  return *reinterpret_cast<unsigned*>(&h);
}

// ---------------- prep: pack weights to 32x32x16 A-fragment layout ----------
// dst[(ct*nkt + kt)*64 + lane]*8 + j == W[ct*32 + (lane&31)][kt*16 + (lane>>5)*8 + j]
__global__ void pack_w(const float* __restrict__ w, ushort* __restrict__ dst,
                       int OUT, int KIN, int nct, int nkt) {
  int t = blockIdx.x * 256 + threadIdx.x;
  int total = nct * nkt * 64;
  if (t >= total) return;
  int l  = t & 63;
  int kt = (t >> 6) % nkt;
  int ct = (t >> 6) / nkt;
  int row = ct * 32 + (l & 31);
  int k0  = kt * 16 + (l >> 5) * 8;
  ushort* d = dst + (size_t)t * 8;
  #pragma unroll
  for (int j = 0; j < 8; ++j) {
    int k = k0 + j;
    float v = (row < OUT && k < KIN) ? w[(size_t)row * KIN + k] : 0.f;
    d[j] = bfu(v);
  }
}

__global__ void pack_b(const float* __restrict__ b, float* __restrict__ dst, int OUT, int OUTP) {
  int i = blockIdx.x * 256 + threadIdx.x;
  if (i < OUTP) dst[i] = (i < OUT) ? b[i] : 0.f;
}

// ---------------- generic 32x32x16 MFMA layer (fragment-major LDS) ----------
// Swapped operands: D = W(A) x Act^T(B). Lane holds 16 output channels
// (rows (reg&3)+8*(reg>>2)+4*(lane>>5) of ch-tile ct) for point (lane&31).
// Epilogue re-fragments via 4 dense b64 stores per tile (transpose by address).
// k-tiles < KSPLIT read a0 (s0 lines per r2), >= KSPLIT read a1 (s1 lines).
template<int NKT, int KSPLIT, int NR, bool RELU>
__device__ __forceinline__ void layerg(
    const ushort* __restrict__ wpk, const float* __restrict__ bias,
    const ushort* a0, int s0, const ushort* a1, int s1,
    ushort* dst, int ct, int r2base, int lane)
{
  const int l5 = lane >> 5;
  f32x4 bq[4];
  #pragma unroll
  for (int qq = 0; qq < 4; ++qq)
    bq[qq] = *(const f32x4*)(bias + ct * 32 + qq * 8 + 4 * l5);
  f32x16 acc[NR];
  #pragma unroll
  for (int rr = 0; rr < NR; ++rr)
    #pragma unroll
    for (int qq = 0; qq < 4; ++qq) {
      acc[rr][qq * 4 + 0] = bq[qq][0];
      acc[rr][qq * 4 + 1] = bq[qq][1];
      acc[rr][qq * 4 + 2] = bq[qq][2];
      acc[rr][qq * 4 + 3] = bq[qq][3];
    }
  #pragma unroll
  for (int kt = 0; kt < NKT; ++kt) {
    short8 bv = *(const short8*)(wpk + (size_t)((ct * NKT + kt) * 64 + lane) * 8);
    #pragma unroll
    for (int rr = 0; rr < NR; ++rr) {
      const int r2 = r2base + rr;
      const ushort* src = (kt < KSPLIT)
          ? a0 + (r2 * s0 + kt) * 512 + lane * 8
          : a1 + (r2 * s1 + (kt - KSPLIT)) * 512 + lane * 8;
      short8 av = *(const short8*)src;
      acc[rr] = __builtin_amdgcn_mfma_f32_32x32x16_bf16(bv, av, acc[rr], 0, 0, 0);
    }
  }
  #pragma unroll
  for (int rr = 0; rr < NR; ++rr) {
    const int r2 = r2base + rr;
    #pragma unroll
    for (int qq = 0; qq < 4; ++qq) {
      float v0 = acc[rr][qq * 4 + 0], v1 = acc[rr][qq * 4 + 1];
      float v2 = acc[rr][qq * 4 + 2], v3 = acc[rr][qq * 4 + 3];
      if (RELU) {
        v0 = fmaxf(v0, 0.f); v1 = fmaxf(v1, 0.f);
        v2 = fmaxf(v2, 0.f); v3 = fmaxf(v3, 0.f);
      }
      uint2 p; p.x = pk2(v0, v1); p.y = pk2(v2, v3);
      *(uint2*)(dst + (r2 * 16 + ct * 2 + (qq >> 1)) * 512
                    + ((lane & 31) + 32 * (qq & 1)) * 8 + 4 * l5) = p;
    }
  }
}

// posenc channel value: c<3 -> x[c]; c<CMAX -> sin/cos(x * 2^l); else 0
__device__ __forceinline__ float pe_val(const float xv[3], int c, int CMAX) {
  if (c < 3) return xv[c];
  if (c < CMAX) {
    int idx = c - 3, l = idx / 6, t = idx - l * 6;
    float f = (float)(1 << l);
    float xx = xv[t < 3 ? t : t - 3];
    return (t < 3) ? __sinf(xx * f) : __cosf(xx * f);
  }
  return 0.f;
}

// ---------------- fused NeRF ----------------
extern __shared__ ushort smem[];

__global__ __launch_bounds__(512, 4) void nerf_fused(
    const float* __restrict__ xyz, const float* __restrict__ dvec,
    const ushort* __restrict__ wp, const float* __restrict__ bp,
    float* __restrict__ out)
{
  ushort* buf0 = smem;
  ushort* buf1 = smem + BUF1_OFF;
  ushort* xbuf = smem + XBUF_OFF;
  const int tid  = threadIdx.x;
  const int row0 = blockIdx.x * ROWS;
  const int wave = tid >> 6, lane = tid & 63;
  const int l5 = lane >> 5;

  // posenc(xyz) -> x_emb fragment lines [r2][kt]: wave w -> r2=w>>2, kt=w&3
  {
    const int r2 = wave >> 2, kt = wave & 3;
    const float* x = xyz + (size_t)(row0 + r2 * 32 + (lane & 31)) * 3;
    float xv[3] = {x[0], x[1], x[2]};
    const int c0 = kt * 16 + l5 * 8;
    unsigned u[4];
    #pragma unroll
    for (int q = 0; q < 4; ++q)
      u[q] = (unsigned)bfu(pe_val(xv, c0 + q * 2, 63))
           | ((unsigned)bfu(pe_val(xv, c0 + q * 2 + 1, 63)) << 16);
    *(uint4*)(xbuf + (r2 * 4 + kt) * 512 + lane * 8) = make_uint4(u[0], u[1], u[2], u[3]);
  }
  __syncthreads();
  layerg<4, 0, 2, true >(wp + 0,      bp + 0,    xbuf, 4, xbuf, 4, buf0, wave, 0, lane);
  __syncthreads();
  layerg<16, 16, 2, true>(wp + 16384,  bp + 256,  buf0, 16, buf0, 16, buf1, wave, 0, lane);
  __syncthreads();
  layerg<16, 16, 2, true>(wp + 81920,  bp + 512,  buf1, 16, buf1, 16, buf0, wave, 0, lane);
  __syncthreads();
  layerg<16, 16, 2, true>(wp + 147456, bp + 768,  buf0, 16, buf0, 16, buf1, wave, 0, lane);
  __syncthreads();
  layerg<16, 16, 2, true>(wp + 212992, bp + 1024, buf1, 16, buf1, 16, buf0, wave, 0, lane);
  __syncthreads();
  // L2_0: K = 256 (buf0) + 64 (x_emb in xbuf)
  layerg<20, 16, 2, true>(wp + 278528, bp + 1280, buf0, 16, xbuf, 4, buf1, wave, 0, lane);
  __syncthreads();
  // d_emb -> xbuf lines [r2][kt2] (x_emb dead; read much later by LR0)
  if (wave < 4) {
    const int r2 = wave >> 1, kt = wave & 1;
    const float* d = dvec + (size_t)(row0 + r2 * 32 + (lane & 31)) * 3;
    float dv[3] = {d[0], d[1], d[2]};
    const int c0 = kt * 16 + l5 * 8;
    unsigned u[4];
    #pragma unroll
    for (int q = 0; q < 4; ++q)
      u[q] = (unsigned)bfu(pe_val(dv, c0 + q * 2, 27))
           | ((unsigned)bfu(pe_val(dv, c0 + q * 2 + 1, 27)) << 16);
    *(uint4*)(xbuf + (r2 * 2 + kt) * 512 + lane * 8) = make_uint4(u[0], u[1], u[2], u[3]);
  }
  layerg<16, 16, 2, true>(wp + 360448, bp + 1536, buf1, 16, buf1, 16, buf0, wave, 0, lane);
  __syncthreads();
  layerg<16, 16, 2, true>(wp + 425984, bp + 1792, buf0, 16, buf0, 16, buf1, wave, 0, lane);
  __syncthreads();
  // L2_3: h (NO relu) -> buf0; sigma (ct=8, ch 256) on waves 0,1 from buf1
  layerg<16, 16, 2, false>(wp + 491520, bp + 2048, buf1, 16, buf1, 16, buf0, wave, 0, lane);
  if (wave < 2) {
    const ushort* w23 = wp + 491520;
    const int r2 = wave;
    f32x16 acc;
    #pragma unroll
    for (int qq = 0; qq < 4; ++qq) {
      f32x4 b4 = *(const f32x4*)(bp + 2048 + 256 + qq * 8 + 4 * l5);
      acc[qq * 4 + 0] = b4[0]; acc[qq * 4 + 1] = b4[1];
      acc[qq * 4 + 2] = b4[2]; acc[qq * 4 + 3] = b4[3];
    }
    #pragma unroll
    for (int kt = 0; kt < 16; ++kt) {
      short8 bv = *(const short8*)(w23 + (size_t)((8 * 16 + kt) * 64 + lane) * 8);
      short8 av = *(const short8*)(buf1 + (r2 * 16 + kt) * 512 + lane * 8);
      acc = __builtin_amdgcn_mfma_f32_32x32x16_bf16(bv, av, acc, 0, 0, 0);
    }
    if (lane < 32)
      out[(size_t)3 * NPTS + row0 + r2 * 32 + lane] = fmaxf(acc[0], 0.f);
  }
  __syncthreads();
  // LR0: K = 256 (buf0) + 32 (d_emb); out 128 = 4 ct x 2 r2 = 1 tile/wave
  layerg<18, 16, 1, true>(wp + 565248, bp + 2336, buf0, 16, xbuf, 2, buf1, wave & 3, wave >> 2, lane);
  __syncthreads();
  // LR1: K = 128 (buf1 kt 0..7), out ch 0..2 -> sigmoid -> out; waves 0,1
  if (wave < 2) {
    const ushort* w = wp + 602112;
    const int r2 = wave;
    f32x16 acc;
    #pragma unroll
    for (int qq = 0; qq < 4; ++qq) {
      f32x4 b4 = *(const f32x4*)(bp + 2464 + qq * 8 + 4 * l5);
      acc[qq * 4 + 0] = b4[0]; acc[qq * 4 + 1] = b4[1];
      acc[qq * 4 + 2] = b4[2]; acc[qq * 4 + 3] = b4[3];
    }
    #pragma unroll
    for (int kt = 0; kt < 8; ++kt) {
      short8 bv = *(const short8*)(w + (size_t)(kt * 64 + lane) * 8);
      short8 av = *(const short8*)(buf1 + (r2 * 16 + kt) * 512 + lane * 8);
      acc = __builtin_amdgcn_mfma_f32_32x32x16_bf16(bv, av, acc, 0, 0, 0);
    }
    if (lane < 32) {
      int p = row0 + r2 * 32 + lane;
      out[(size_t)p * 3 + 0] = 1.f / (1.f + __expf(-acc[0]));
      out[(size_t)p * 3 + 1] = 1.f / (1.f + __expf(-acc[1]));
      out[(size_t)p * 3 + 2] = 1.f / (1.f + __expf(-acc[2]));
    }
  }
}

// ---------------- host ----------------
extern "C" void kernel_launch(void* const* d_in, const int* in_sizes, int n_in,
                              void* d_out, int out_size, void* d_ws, size_t ws_size,
                              hipStream_t stream) {
  const float* xyz  = (const float*)d_in[0];
  const float* dvec = (const float*)d_in[1];
  ushort* wp = (ushort*)d_ws;
  float*  bp = (float*)((char*)d_ws + 1212416);

  struct WSpec { int idx, OUT, KIN, nct, nkt, off; };
  const WSpec wspecs[11] = {
    { 2, 256,  63, 8,  4,      0},
    { 4, 256, 256, 8, 16,  16384},
    { 6, 256, 256, 8, 16,  81920},
    { 8, 256, 256, 8, 16, 147456},
    {10, 256, 256, 8, 16, 212992},
    {12, 256, 319, 8, 20, 278528},
    {14, 256, 256, 8, 16, 360448},
    {16, 256, 256, 8, 16, 425984},
    {18, 257, 256, 9, 16, 491520},
    {20, 128, 283, 4, 18, 565248},
    {22,   3, 128, 1,  8, 602112},
  };
  for (int i = 0; i < 11; ++i) {
    int total = wspecs[i].nct * wspecs[i].nkt * 64;
    pack_w<<<dim3((total + 255) / 256), dim3(256), 0, stream>>>(
      (const float*)d_in[wspecs[i].idx], wp + wspecs[i].off,
      wspecs[i].OUT, wspecs[i].KIN, wspecs[i].nct, wspecs[i].nkt);
  }
  struct BSpec { int idx, OUT, OUTP, off; };
  const BSpec bspecs[11] = {
    { 3, 256, 256,    0}, { 5, 256, 256,  256}, { 7, 256, 256,  512}, { 9, 256, 256,  768},
    {11, 256, 256, 1024}, {13, 256, 256, 1280}, {15, 256, 256, 1536}, {17, 256, 256, 1792},
    {19, 257, 288, 2048}, {21, 128, 128, 2336}, {23,   3,  32, 2464},
  };
  for (int i = 0; i < 11; ++i) {
    pack_b<<<dim3((bspecs[i].OUTP + 255) / 256), dim3(256), 0, stream>>>(
      (const float*)d_in[bspecs[i].idx], bp + bspecs[i].off, bspecs[i].OUT, bspecs[i].OUTP);
  }

  hipFuncSetAttribute(reinterpret_cast<const void*>(nerf_fused),
                      hipFuncAttributeMaxDynamicSharedMemorySize, LDS_BYTES);
  nerf_fused<<<dim3(NPTS / ROWS), dim3(512), LDS_BYTES, stream>>>(xyz, dvec, wp, bp, (float*)d_out);
}